// Round 5
// baseline (283.291 us; speedup 1.0000x reference)
//
#include <hip/hip_runtime.h>
#include <stdint.h>

typedef float  f32x4  __attribute__((ext_vector_type(4)));
typedef short  s16x8  __attribute__((ext_vector_type(8)));
typedef unsigned int u32x4 __attribute__((ext_vector_type(4)));
typedef unsigned short ushort_t;
typedef unsigned int uint_t;

#define B_  4
#define S_  2048
#define E_  2048
#define DH_ 256

#define MFMA16(a,b,c) __builtin_amdgcn_mfma_f32_16x16x32_bf16((a),(b),(c),0,0,0)

#define GL16(gp, lp) __builtin_amdgcn_global_load_lds( \
    (const __attribute__((address_space(1))) unsigned int*)(gp), \
    (__attribute__((address_space(3))) unsigned int*)(lp), 16, 0, 0)

__device__ __forceinline__ ushort_t f2b(float f){
  unsigned u = __builtin_bit_cast(unsigned, f);
  u += 0x7fffu + ((u >> 16) & 1u);   // RNE
  return (ushort_t)(u >> 16);
}

// ---------------- x fp32 -> bf16 ----------------
__global__ __launch_bounds__(256) void k_convert_x(const float* __restrict__ x,
                                                   ushort_t* __restrict__ xbf){
  size_t i = ((size_t)blockIdx.x * 256 + threadIdx.x) * 8;
  f32x4 a = *(const f32x4*)(x + i);
  f32x4 b = *(const f32x4*)(x + i + 4);
  union { ushort_t us[8]; u32x4 v; } u;
#pragma unroll
  for (int j = 0; j < 4; ++j){ u.us[j] = f2b(a[j]); u.us[4+j] = f2b(b[j]); }
  *(u32x4*)(xbf + i) = u.v;
}

// ---------------- W[2048][256] -> Wt bf16 [3][256][2048] ----------------
__global__ __launch_bounds__(256) void k_transpose_w(const float* __restrict__ Wq,
                                                     const float* __restrict__ Wk,
                                                     const float* __restrict__ Wv,
                                                     ushort_t* __restrict__ Wt){
  __shared__ ushort_t tile[32][33];
  int z = blockIdx.z;
  const float* W = (z == 0) ? Wq : ((z == 1) ? Wk : Wv);
  int k0 = blockIdx.x * 32, n0 = blockIdx.y * 32;
  int t = threadIdx.x, tx = t & 31, ty = t >> 5;
#pragma unroll
  for (int i = 0; i < 4; ++i)
    tile[ty + i*8][tx] = f2b(W[(size_t)(k0 + ty + i*8) * DH_ + n0 + tx]);
  __syncthreads();
#pragma unroll
  for (int i = 0; i < 4; ++i)
    Wt[(size_t)z * DH_ * E_ + (size_t)(n0 + ty + i*8) * E_ + k0 + tx] = tile[tx][ty + i*8];
}

// ------- padding mask (bool-bytes OR int32) -> u32 bitmask per 32-key tile -------
__global__ __launch_bounds__(256) void k_prep_pad(const unsigned char* __restrict__ pm,
                                                  uint_t* __restrict__ padbits){
  int t = threadIdx.x;
  // detect layout: any nonzero byte at offset%4!=0 within first 8192B => bool layout
  const u32x4* p4 = (const u32x4*)pm;
  int any = 0;
#pragma unroll
  for (int i = 0; i < 2; ++i){
    u32x4 v = p4[t + i * 256];
    uint_t x = (v[0] | v[1] | v[2] | v[3]) & 0xFFFFFF00u;
    any |= (x != 0);
  }
  int isb = __syncthreads_or(any);
  uint_t bits = 0;
  int base = (t >> 6) * S_ + (t & 63) * 32;
  if (isb){
#pragma unroll
    for (int j = 0; j < 32; ++j) bits |= (pm[base + j] ? 1u : 0u) << j;
  } else {
    const uint_t* pw = (const uint_t*)pm;
#pragma unroll
    for (int j = 0; j < 32; ++j) bits |= (pw[base + j] ? 1u : 0u) << j;
  }
  padbits[t] = bits;
}

// ---- QKV GEMM, z-fused: 64x64 tile x 3 outputs, BK=64, 2-phase dbuf global_load_lds ----
__global__ __launch_bounds__(256) void k_gemm_qkv(const ushort_t* __restrict__ xbf,
                                                  const ushort_t* __restrict__ Wt,
                                                  const float* __restrict__ bQ,
                                                  const float* __restrict__ bK,
                                                  const float* __restrict__ bV,
                                                  ushort_t* __restrict__ Qo,
                                                  ushort_t* __restrict__ Ko,
                                                  ushort_t* __restrict__ Vo){
  __shared__ __align__(16) ushort_t Ad[2][64 * 64];      // linear, src pre-swizzled
  __shared__ __align__(16) ushort_t Bd[2][3][64 * 64];
  int m0 = blockIdx.x * 64, n0 = blockIdx.y * 64;
  int t = threadIdx.x;
  int lane = t & 63, w = t >> 6, lo = lane & 15, grp = lane >> 4;
  int wm = w >> 1, wn = w & 1;                            // 2x2 waves, 32x32 each

  f32x4 z4; z4[0] = z4[1] = z4[2] = z4[3] = 0.f;
  f32x4 acc[3][2][2];
#pragma unroll
  for (int z = 0; z < 3; ++z)
#pragma unroll
    for (int mt = 0; mt < 2; ++mt){ acc[z][mt][0] = z4; acc[z][mt][1] = z4; }

  auto stage = [&](int buf, int k0){
    // A: 8KB, 2 instrs/wave
#pragma unroll
    for (int j = 0; j < 2; ++j){
      int off = w * 2048 + j * 1024;                      // wave-uniform byte base
      int row = (off >> 7) + (lane >> 3);
      int c = lane & 7;
      const ushort_t* src = xbf + (size_t)(m0 + row) * E_ + k0 + ((c ^ (row & 7)) * 8);
      GL16(src, (char*)Ad[buf] + off);
    }
    // B: 3 x 8KB, 6 instrs/wave
#pragma unroll
    for (int j = 0; j < 6; ++j){
      int z = j >> 1, jj = j & 1;
      int off = jj * 4096 + w * 1024;
      int row = (off >> 7) + (lane >> 3);
      int c = lane & 7;
      const ushort_t* src = Wt + (size_t)z * DH_ * E_ + (size_t)(n0 + row) * E_ + k0
                               + ((c ^ (row & 7)) * 8);
      GL16(src, (char*)Bd[buf][z] + off);
    }
  };

  stage(0, 0);
  __syncthreads();
  int cur = 0;
  for (int kt = 0; kt < 32; ++kt){
    if (kt + 1 < 32) stage(cur ^ 1, (kt + 1) * 64);       // prefetch overlaps compute
#pragma unroll
    for (int kk = 0; kk < 2; ++kk){
      s16x8 av[2], bv[3][2];
#pragma unroll
      for (int mt = 0; mt < 2; ++mt){
        int row = wm * 32 + mt * 16 + lo;
        av[mt] = *(const s16x8*)((char*)Ad[cur] +
                  ((row * 128 + kk * 64 + grp * 16) ^ ((row & 7) << 4)));
      }
#pragma unroll
      for (int z = 0; z < 3; ++z)
#pragma unroll
        for (int nt = 0; nt < 2; ++nt){
          int row = wn * 32 + nt * 16 + lo;
          bv[z][nt] = *(const s16x8*)((char*)Bd[cur][z] +
                        ((row * 128 + kk * 64 + grp * 16) ^ ((row & 7) << 4)));
        }
#pragma unroll
      for (int z = 0; z < 3; ++z)
#pragma unroll
        for (int mt = 0; mt < 2; ++mt)
#pragma unroll
          for (int nt = 0; nt < 2; ++nt)
            acc[z][mt][nt] = MFMA16(av[mt], bv[z][nt], acc[z][mt][nt]);
    }
    __syncthreads();   // drains stage vmcnt + compute lgkm; one barrier per K-tile
    cur ^= 1;
  }

#pragma unroll
  for (int z = 0; z < 3; ++z){
    const float* bias = (z == 0) ? bQ : ((z == 1) ? bK : bV);
    ushort_t* out = (z == 0) ? Qo : ((z == 1) ? Ko : Vo);
#pragma unroll
    for (int nt = 0; nt < 2; ++nt){
      int col = n0 + wn * 32 + nt * 16 + lo;
      float bb = bias[col];
#pragma unroll
      for (int mt = 0; mt < 2; ++mt)
#pragma unroll
        for (int r = 0; r < 4; ++r){
          int row = m0 + wm * 32 + mt * 16 + grp * 4 + r;
          out[(size_t)row * DH_ + col] = f2b(acc[z][mt][nt][r] + bb);
        }
    }
  }
}

// ---------------- V[8192][256] -> Vt bf16 [4][256][2048] ----------------
__global__ __launch_bounds__(256) void k_transpose_v(const ushort_t* __restrict__ V,
                                                     ushort_t* __restrict__ Vt){
  __shared__ ushort_t tile[32][33];
  int r0 = blockIdx.x * 32, c0 = blockIdx.y * 32;
  int t = threadIdx.x, tx = t & 31, ty = t >> 5;
#pragma unroll
  for (int i = 0; i < 4; ++i)
    tile[ty + i*8][tx] = V[(size_t)(r0 + ty + i*8) * DH_ + c0 + tx];
  __syncthreads();
  int b = r0 >> 11, s0 = r0 & (S_ - 1);
#pragma unroll
  for (int i = 0; i < 4; ++i)
    Vt[(size_t)(b * DH_ + c0 + ty + i*8) * S_ + s0 + tx] = tile[tx][ty + i*8];
}

// --- flash attention: block = 32 q rows, 8 waves key-split, QBLK=32/wave, KVBLK=64 ---
// Swapped QK^T: mfma(K, Q) -> lane holds scores for q = lane&15 (per q-fragment).
__global__ __launch_bounds__(512) void k_attn(const ushort_t* __restrict__ Q,
                                              const ushort_t* __restrict__ K,
                                              const ushort_t* __restrict__ Vt,
                                              const uint_t* __restrict__ padbits,
                                              float* __restrict__ out){
  __shared__ __align__(16) ushort_t Qs[32 * 256];   // swizzled [row][k], 16KB
  __shared__ __align__(16) ushort_t P[8][2][16][72];
  __shared__ float Osum[32][260];
  __shared__ float ml[8][32][2];
  __shared__ float Linv[32];
  int blk = blockIdx.x;
  int b = blk & (B_ - 1);                  // one batch per XCD: K/Vt L2-resident
  int qt = (S_ / 32 - 1) - (blk >> 2);     // deepest q-tiles launch first
  int t = threadIdx.x;
  int lane = t & 63, w = t >> 6, lo = lane & 15, grp = lane >> 4;
  int qbase = qt * 32;
  const float NEG = -__builtin_inff();
  const float MSENT = -1e30f;

  // stage Q (32 rows) into swizzled LDS via global_load_lds
#pragma unroll
  for (int j = 0; j < 2; ++j){
    int off = w * 2048 + j * 1024;
    int row = (off >> 9) + (lane >> 5);
    int c = lane & 31;
    const ushort_t* src = Q + (size_t)(b * S_ + qbase + row) * DH_ + ((c ^ (row & 7)) * 8);
    GL16(src, (char*)Qs + off);
  }
  __syncthreads();

  f32x4 z4; z4[0] = z4[1] = z4[2] = z4[3] = 0.f;
  f32x4 o[16][2];
#pragma unroll
  for (int i = 0; i < 16; ++i){ o[i][0] = z4; o[i][1] = z4; }
  float m_[2] = { MSENT, MSENT };
  float l_[2] = { 0.f, 0.f };

  int nt64 = ((qbase + 31) >> 6) + 1;

  for (int kt = w; kt < nt64; kt += 8){
    int k0 = kt * 64;
    bool full = (k0 + 63 <= qbase);
    f32x4 sc[4][2];
#pragma unroll
    for (int h = 0; h < 4; ++h){ sc[h][0] = z4; sc[h][1] = z4; }
#pragma unroll
    for (int d = 0; d < 8; ++d){
      s16x8 aq0 = *(const s16x8*)((char*)Qs + (lo * 512 + ((d * 64 + grp * 16) ^ ((lo & 7) << 4))));
      s16x8 aq1 = *(const s16x8*)((char*)Qs + ((16 + lo) * 512 + ((d * 64 + grp * 16) ^ ((lo & 7) << 4))));
#pragma unroll
      for (int h = 0; h < 4; ++h){
        s16x8 kf = *(const s16x8*)(K + (size_t)(b * S_ + k0 + h * 16 + lo) * DH_ + d * 32 + grp * 8);
        sc[h][0] = MFMA16(kf, aq0, sc[h][0]);
        sc[h][1] = MFMA16(kf, aq1, sc[h][1]);
      }
    }
    // scale + padding + causal
    uint_t pb0 = padbits[b * 64 + kt * 2];
    uint_t pb1 = padbits[b * 64 + kt * 2 + 1];
#pragma unroll
    for (int h = 0; h < 4; ++h){
      uint_t bg = ((h < 2 ? pb0 : pb1) >> ((h & 1) * 16)) >> (4 * grp);
#pragma unroll
      for (int qf = 0; qf < 2; ++qf)
#pragma unroll
        for (int r = 0; r < 4; ++r){
          float v = sc[h][qf][r] * 0.0625f;          // 1/sqrt(256)
          sc[h][qf][r] = ((bg >> r) & 1) ? NEG : v;
        }
    }
    if (!full){
#pragma unroll
      for (int qf = 0; qf < 2; ++qf){
        int q = qbase + qf * 16 + lo;
#pragma unroll
        for (int h = 0; h < 4; ++h)
#pragma unroll
          for (int r = 0; r < 4; ++r)
            if (k0 + h * 16 + 4 * grp + r > q) sc[h][qf][r] = NEG;
      }
    }
    // online softmax per q-fragment
#pragma unroll
    for (int qf = 0; qf < 2; ++qf){
      float mt0 = fmaxf(fmaxf(sc[0][qf][0], sc[0][qf][1]), fmaxf(sc[0][qf][2], sc[0][qf][3]));
      float mt1 = fmaxf(fmaxf(sc[1][qf][0], sc[1][qf][1]), fmaxf(sc[1][qf][2], sc[1][qf][3]));
      float mt2 = fmaxf(fmaxf(sc[2][qf][0], sc[2][qf][1]), fmaxf(sc[2][qf][2], sc[2][qf][3]));
      float mt3 = fmaxf(fmaxf(sc[3][qf][0], sc[3][qf][1]), fmaxf(sc[3][qf][2], sc[3][qf][3]));
      float mt = fmaxf(fmaxf(mt0, mt1), fmaxf(mt2, mt3));
      mt = fmaxf(mt, __shfl_xor(mt, 16));
      mt = fmaxf(mt, __shfl_xor(mt, 32));
      if (__any(mt > m_[qf] + 8.f)){                 // deferred rescale, THR=8
        float mn = fmaxf(m_[qf], mt);
        float al = __expf(m_[qf] - mn);
        m_[qf] = mn;
        l_[qf] *= al;
        float a0 = __shfl(al, 4 * grp + 0);
        float a1 = __shfl(al, 4 * grp + 1);
        float a2 = __shfl(al, 4 * grp + 2);
        float a3 = __shfl(al, 4 * grp + 3);
#pragma unroll
        for (int i = 0; i < 16; ++i){
          o[i][qf][0] *= a0; o[i][qf][1] *= a1; o[i][qf][2] *= a2; o[i][qf][3] *= a3;
        }
      }
      float ls = 0.f;
#pragma unroll
      for (int h = 0; h < 4; ++h)
#pragma unroll
        for (int r = 0; r < 4; ++r){
          float p = __expf(sc[h][qf][r] - m_[qf]);
          sc[h][qf][r] = p;
          ls += p;
        }
      ls += __shfl_xor(ls, 16);
      ls += __shfl_xor(ls, 32);
      l_[qf] += ls;
      // P -> LDS bf16 (row = q = lo)
      char* prow = (char*)&P[w][qf][lo][0];
#pragma unroll
      for (int h = 0; h < 4; ++h){
        uint_t u0 = (uint_t)f2b(sc[h][qf][0]) | ((uint_t)f2b(sc[h][qf][1]) << 16);
        uint_t u1 = (uint_t)f2b(sc[h][qf][2]) | ((uint_t)f2b(sc[h][qf][3]) << 16);
        *(uint_t*)(prow + h * 32 + grp * 8)     = u0;
        *(uint_t*)(prow + h * 32 + grp * 8 + 4) = u1;
      }
    }
    s16x8 pa0[2], pa1[2];
#pragma unroll
    for (int qf = 0; qf < 2; ++qf){
      char* prow = (char*)&P[w][qf][lo][0];
      pa0[qf] = *(const s16x8*)(prow + grp * 16);
      pa1[qf] = *(const s16x8*)(prow + 64 + grp * 16);
    }
#pragma unroll
    for (int i = 0; i < 16; ++i){
      s16x8 v0 = *(const s16x8*)(Vt + (size_t)(b * DH_ + i * 16 + lo) * S_ + k0 + grp * 8);
      s16x8 v1 = *(const s16x8*)(Vt + (size_t)(b * DH_ + i * 16 + lo) * S_ + k0 + 32 + grp * 8);
      o[i][0] = MFMA16(pa0[0], v0, o[i][0]);
      o[i][0] = MFMA16(pa1[0], v1, o[i][0]);
      o[i][1] = MFMA16(pa0[1], v0, o[i][1]);
      o[i][1] = MFMA16(pa1[1], v1, o[i][1]);
    }
  }

  // m,l to output layout (q = qf*16 + grp*4 + r)
  float mo[2][4], lo_[2][4];
#pragma unroll
  for (int qf = 0; qf < 2; ++qf)
#pragma unroll
    for (int r = 0; r < 4; ++r){
      mo[qf][r]  = __shfl(m_[qf], 4 * grp + r);
      lo_[qf][r] = __shfl(l_[qf], 4 * grp + r);
    }

  if (lo == 0){
#pragma unroll
    for (int qf = 0; qf < 2; ++qf)
#pragma unroll
      for (int r = 0; r < 4; ++r){
        ml[w][qf * 16 + grp * 4 + r][0] = mo[qf][r];
        ml[w][qf * 16 + grp * 4 + r][1] = lo_[qf][r];
      }
  }
  __syncthreads();
  float sc2[2][4];
#pragma unroll
  for (int qf = 0; qf < 2; ++qf)
#pragma unroll
    for (int r = 0; r < 4; ++r){
      int row = qf * 16 + grp * 4 + r;
      float Mx = MSENT;
#pragma unroll
      for (int ww = 0; ww < 8; ++ww) Mx = fmaxf(Mx, ml[ww][row][0]);
      float Ls = 0.f;
#pragma unroll
      for (int ww = 0; ww < 8; ++ww) Ls += ml[ww][row][1] * __expf(ml[ww][row][0] - Mx);
      sc2[qf][r] = __expf(mo[qf][r] - Mx);
      if (w == 0 && lo == 0) Linv[row] = 1.0f / Ls;
    }
#pragma unroll
  for (int i = 0; i < 16; ++i)
#pragma unroll
    for (int qf = 0; qf < 2; ++qf)
#pragma unroll
      for (int r = 0; r < 4; ++r) o[i][qf][r] *= sc2[qf][r];
  for (int ww = 0; ww < 8; ++ww){
    if (w == ww){
#pragma unroll
      for (int i = 0; i < 16; ++i)
#pragma unroll
        for (int qf = 0; qf < 2; ++qf)
#pragma unroll
          for (int r = 0; r < 4; ++r){
            float* p = &Osum[qf * 16 + grp * 4 + r][i * 16 + lo];
            if (ww == 0) *p = o[i][qf][r]; else *p += o[i][qf][r];
          }
    }
    __syncthreads();
  }
  int row = t >> 4, sub = t & 15;
  float li = Linv[row];
  float* ob = out + (size_t)(b * S_ + qbase + row) * DH_ + sub * 16;
#pragma unroll
  for (int j = 0; j < 4; ++j){
    f32x4 v;
    v[0] = Osum[row][sub * 16 + j * 4 + 0] * li;
    v[1] = Osum[row][sub * 16 + j * 4 + 1] * li;
    v[2] = Osum[row][sub * 16 + j * 4 + 2] * li;
    v[3] = Osum[row][sub * 16 + j * 4 + 3] * li;
    *(f32x4*)(ob + j * 4) = v;
  }
}

extern "C" void kernel_launch(void* const* d_in, const int* in_sizes, int n_in,
                              void* d_out, int out_size, void* d_ws, size_t ws_size,
                              hipStream_t stream){
  const float* x          = (const float*)d_in[0];
  // d_in[1] = causal_mask (semantics fixed: lower-triangular) — not read
  const unsigned char* pm = (const unsigned char*)d_in[2];
  const float* Wq = (const float*)d_in[3];
  const float* bQ = (const float*)d_in[4];
  const float* Wk = (const float*)d_in[5];
  const float* bK = (const float*)d_in[6];
  const float* Wv = (const float*)d_in[7];
  const float* bV = (const float*)d_in[8];
  float* out = (float*)d_out;

  char* ws = (char*)d_ws;
  ushort_t* xbf  = (ushort_t*)(ws);              // 33,554,432 B
  ushort_t* Wt   = (ushort_t*)(ws + 33554432);   //  3,145,728 B
  ushort_t* Qb   = (ushort_t*)(ws + 36700160);   //  4,194,304 B
  ushort_t* Kb   = (ushort_t*)(ws + 40894464);   //  4,194,304 B
  ushort_t* Vb   = (ushort_t*)(ws + 45088768);   //  4,194,304 B
  ushort_t* Vt   = (ushort_t*)(ws + 49283072);   //  4,194,304 B
  uint_t*   padbits = (uint_t*)(ws + 53477376);  //      1,024 B

  k_convert_x  <<<dim3(8192),       dim3(256), 0, stream>>>(x, xbf);
  k_transpose_w<<<dim3(64, 8, 3),   dim3(256), 0, stream>>>(Wq, Wk, Wv, Wt);
  k_prep_pad   <<<dim3(1),          dim3(256), 0, stream>>>(pm, padbits);
  k_gemm_qkv   <<<dim3(128, 4),     dim3(256), 0, stream>>>(xbf, Wt, bQ, bK, bV, Qb, Kb, Vb);
  k_transpose_v<<<dim3(256, 8),     dim3(256), 0, stream>>>(Vb, Vt);
  k_attn       <<<dim3(256),        dim3(512), 0, stream>>>(Qb, Kb, Vt, padbits, out);
}

// Round 7
// 241.202 us; speedup vs baseline: 1.1745x; 1.1745x over previous
//
#include <hip/hip_runtime.h>
#include <stdint.h>

typedef float  f32x4  __attribute__((ext_vector_type(4)));
typedef short  s16x8  __attribute__((ext_vector_type(8)));
typedef unsigned int u32x4 __attribute__((ext_vector_type(4)));
typedef unsigned short ushort_t;
typedef unsigned int uint_t;

#define B_  4
#define S_  2048
#define E_  2048
#define DH_ 256

#define MFMA16(a,b,c) __builtin_amdgcn_mfma_f32_16x16x32_bf16((a),(b),(c),0,0,0)

#define GL16(gp, lp) __builtin_amdgcn_global_load_lds( \
    (const __attribute__((address_space(1))) unsigned int*)(gp), \
    (__attribute__((address_space(3))) unsigned int*)(lp), 16, 0, 0)

__device__ __forceinline__ ushort_t f2b(float f){
  unsigned u = __builtin_bit_cast(unsigned, f);
  u += 0x7fffu + ((u >> 16) & 1u);   // RNE
  return (ushort_t)(u >> 16);
}
__device__ __forceinline__ float b2f(ushort_t u){
  return __builtin_bit_cast(float, ((unsigned)u) << 16);
}

// ---------------- x fp32 -> bf16 ----------------
__global__ __launch_bounds__(256) void k_convert_x(const float* __restrict__ x,
                                                   ushort_t* __restrict__ xbf){
  size_t i = ((size_t)blockIdx.x * 256 + threadIdx.x) * 8;
  f32x4 a = *(const f32x4*)(x + i);
  f32x4 b = *(const f32x4*)(x + i + 4);
  union { ushort_t us[8]; u32x4 v; } u;
#pragma unroll
  for (int j = 0; j < 4; ++j){ u.us[j] = f2b(a[j]); u.us[4+j] = f2b(b[j]); }
  *(u32x4*)(xbf + i) = u.v;
}

// ---------------- W[2048][256] -> Wt bf16 [3][256][2048] ----------------
__global__ __launch_bounds__(256) void k_transpose_w(const float* __restrict__ Wq,
                                                     const float* __restrict__ Wk,
                                                     const float* __restrict__ Wv,
                                                     ushort_t* __restrict__ Wt){
  __shared__ ushort_t tile[32][33];
  int z = blockIdx.z;
  const float* W = (z == 0) ? Wq : ((z == 1) ? Wk : Wv);
  int k0 = blockIdx.x * 32, n0 = blockIdx.y * 32;
  int t = threadIdx.x, tx = t & 31, ty = t >> 5;
#pragma unroll
  for (int i = 0; i < 4; ++i)
    tile[ty + i*8][tx] = f2b(W[(size_t)(k0 + ty + i*8) * DH_ + n0 + tx]);
  __syncthreads();
#pragma unroll
  for (int i = 0; i < 4; ++i)
    Wt[(size_t)z * DH_ * E_ + (size_t)(n0 + ty + i*8) * E_ + k0 + tx] = tile[tx][ty + i*8];
}

// ------- padding mask (bool-bytes OR int32) -> u32 bitmask per 32-key tile -------
__global__ __launch_bounds__(256) void k_prep_pad(const unsigned char* __restrict__ pm,
                                                  uint_t* __restrict__ padbits){
  int t = threadIdx.x;
  const u32x4* p4 = (const u32x4*)pm;
  int any = 0;
#pragma unroll
  for (int i = 0; i < 2; ++i){
    u32x4 v = p4[t + i * 256];
    uint_t x = (v[0] | v[1] | v[2] | v[3]) & 0xFFFFFF00u;
    any |= (x != 0);
  }
  int isb = __syncthreads_or(any);
  uint_t bits = 0;
  int base = (t >> 6) * S_ + (t & 63) * 32;
  if (isb){
#pragma unroll
    for (int j = 0; j < 32; ++j) bits |= (pm[base + j] ? 1u : 0u) << j;
  } else {
    const uint_t* pw = (const uint_t*)pm;
#pragma unroll
    for (int j = 0; j < 32; ++j) bits |= (pw[base + j] ? 1u : 0u) << j;
  }
  padbits[t] = bits;
}

// ---- QKV GEMM: m97-style 128x128 tile, BK=64, global_load_lds, 2 barriers/K-step ----
// B = Wt viewed as [768][2048]; output z = by>>1 (no z-boundary crossing per block).
__global__ __launch_bounds__(256) void k_gemm_qkv(const ushort_t* __restrict__ xbf,
                                                  const ushort_t* __restrict__ Wt,
                                                  const float* __restrict__ bQ,
                                                  const float* __restrict__ bK,
                                                  const float* __restrict__ bV,
                                                  ushort_t* __restrict__ Qo,
                                                  ushort_t* __restrict__ Ko,
                                                  ushort_t* __restrict__ Vo){
  __shared__ __align__(16) ushort_t Al[128 * 64];   // linear, src pre-swizzled
  __shared__ __align__(16) ushort_t Bl[128 * 64];
  int m0 = blockIdx.x * 128;
  int by = blockIdx.y;
  int n0 = by * 128;
  int z  = by >> 1;
  const float* bias = (z == 0) ? bQ : ((z == 1) ? bK : bV);
  ushort_t* out = (z == 0) ? Qo : ((z == 1) ? Ko : Vo);
  int t = threadIdx.x;
  int lane = t & 63, w = t >> 6, lo = lane & 15, grp = lane >> 4;
  int wm = w >> 1, wn = w & 1;                      // 2x2 waves, each 64x64 out

  f32x4 z4; z4[0] = z4[1] = z4[2] = z4[3] = 0.f;
  f32x4 acc[4][4];
#pragma unroll
  for (int mt = 0; mt < 4; ++mt)
#pragma unroll
    for (int nt = 0; nt < 4; ++nt) acc[mt][nt] = z4;

  for (int k0 = 0; k0 < E_; k0 += 64){
    // stage A,B: 16KB each, 4 GL16/thread each
#pragma unroll
    for (int j = 0; j < 4; ++j){
      int off = t * 16 + j * 4096;
      int row = off >> 7, c = (off >> 4) & 7;
      GL16(xbf + (size_t)(m0 + row) * E_ + k0 + ((c ^ (row & 7)) * 8), (char*)Al + off);
      GL16(Wt  + (size_t)(n0 + row) * E_ + k0 + ((c ^ (row & 7)) * 8), (char*)Bl + off);
    }
    __syncthreads();   // vmcnt(0) drain: tiles ready
#pragma unroll
    for (int kk = 0; kk < 2; ++kk){
      s16x8 av[4], bv[4];
#pragma unroll
      for (int mt = 0; mt < 4; ++mt){
        int row = wm * 64 + mt * 16 + lo;
        av[mt] = *(const s16x8*)((char*)Al + ((row * 128 + kk * 64 + grp * 16) ^ ((row & 7) << 4)));
      }
#pragma unroll
      for (int nt = 0; nt < 4; ++nt){
        int row = wn * 64 + nt * 16 + lo;
        bv[nt] = *(const s16x8*)((char*)Bl + ((row * 128 + kk * 64 + grp * 16) ^ ((row & 7) << 4)));
      }
#pragma unroll
      for (int mt = 0; mt < 4; ++mt)
#pragma unroll
        for (int nt = 0; nt < 4; ++nt)
          acc[mt][nt] = MFMA16(av[mt], bv[nt], acc[mt][nt]);
    }
    __syncthreads();   // all reads done before restage
  }
#pragma unroll
  for (int nt = 0; nt < 4; ++nt){
    int colz = (by & 1) * 128 + wn * 64 + nt * 16 + lo;   // col within 256
    float bb = bias[colz];
#pragma unroll
    for (int mt = 0; mt < 4; ++mt)
#pragma unroll
      for (int r = 0; r < 4; ++r){
        int row = m0 + wm * 64 + mt * 16 + grp * 4 + r;
        out[(size_t)row * DH_ + colz] = f2b(acc[mt][nt][r] + bb);
      }
  }
}

// ---------------- V[8192][256] -> Vt bf16 [4][256][2048] ----------------
__global__ __launch_bounds__(256) void k_transpose_v(const ushort_t* __restrict__ V,
                                                     ushort_t* __restrict__ Vt){
  __shared__ ushort_t tile[32][33];
  int r0 = blockIdx.x * 32, c0 = blockIdx.y * 32;
  int t = threadIdx.x, tx = t & 31, ty = t >> 5;
#pragma unroll
  for (int i = 0; i < 4; ++i)
    tile[ty + i*8][tx] = V[(size_t)(r0 + ty + i*8) * DH_ + c0 + tx];
  __syncthreads();
  int b = r0 >> 11, s0 = r0 & (S_ - 1);
#pragma unroll
  for (int i = 0; i < 4; ++i)
    Vt[(size_t)(b * DH_ + c0 + ty + i*8) * S_ + s0 + tx] = tile[tx][ty + i*8];
}

// ---- flash attention phase A: block = (split s, q-panel qp, batch b) ----
// 8 waves x 16 private q-rows = 128 q-rows/block; K/V chunk (<=256 keys) staged
// in LDS (dbuf, shared by all waves). Partial O (bf16) + m,l (f32) to ws.
__global__ __launch_bounds__(512) void k_attn_part(const ushort_t* __restrict__ Q,
                                                   const ushort_t* __restrict__ K,
                                                   const ushort_t* __restrict__ Vt,
                                                   const uint_t* __restrict__ padbits,
                                                   ushort_t* __restrict__ Opart,
                                                   float* __restrict__ mlp){
  __shared__ __align__(16) ushort_t Kl[2][64 * 256];   // 2 x 32KB, [key][d]
  __shared__ __align__(16) ushort_t Vl[2][256 * 64];   // 2 x 32KB, [d][key]
  __shared__ __align__(16) ushort_t P[8][16][72];      // per-wave P rows (q=lo)
  int s  = blockIdx.x;            // key chunk
  int qp = blockIdx.y;            // q panel (128 rows)
  int b  = blockIdx.z;
  int nch = (qp >> 1) + 1;
  if (s >= nch) return;
  int pre = qp + ((qp - 1) * (qp - 1)) / 4;            // sum of nch(j), j<qp
  int slot = b * 72 + pre + s;
  int qbase = qp * 128;
  int kstart = s * 256;
  int kend = kstart + 256; if (kend > qbase + 128) kend = qbase + 128;
  int ntile = (kend - kstart) >> 6;                    // 2 or 4

  int t = threadIdx.x;
  int lane = t & 63, w = t >> 6, lo = lane & 15, grp = lane >> 4;
  int qrow0 = qbase + w * 16;
  const float NEG = -__builtin_inff();
  const float MSENT = -1e30f;

  // cooperative stage of one 64-key tile (K 32KB + V 32KB), src pre-swizzled
  auto stage = [&](int buf, int kt){
#pragma unroll
    for (int j = 0; j < 4; ++j){
      int off = t * 16 + j * 8192;
      int krow = off >> 9, kc = (off >> 4) & 31;
      GL16(K + (size_t)(b * S_ + kt + krow) * DH_ + ((kc ^ (krow & 7)) * 8),
           (char*)Kl[buf] + off);
      int vrow = off >> 7, vc = (off >> 4) & 7;
      GL16(Vt + (size_t)(b * DH_ + vrow) * S_ + kt + ((vc ^ (vrow & 7)) * 8),
           (char*)Vl[buf] + off);
    }
  };

  stage(0, kstart);

  // Q fragments (global, once)
  s16x8 aq[8];
#pragma unroll
  for (int d = 0; d < 8; ++d)
    aq[d] = *(const s16x8*)(Q + (size_t)(b * S_ + qrow0 + lo) * DH_ + d * 32 + grp * 8);

  f32x4 z4; z4[0] = z4[1] = z4[2] = z4[3] = 0.f;
  f32x4 o[16];
#pragma unroll
  for (int i = 0; i < 16; ++i) o[i] = z4;
  float m_lo = MSENT, l_lo = 0.f;

  __syncthreads();
  int cur = 0;
  for (int tt = 0; tt < ntile; ++tt){
    if (tt + 1 < ntile) stage(cur ^ 1, kstart + (tt + 1) * 64);
    int kt = kstart + tt * 64;
    if (kt <= qrow0 + 15){                 // wave has >=1 visible key in tile
      bool full = (kt + 63 <= qrow0);      // no causal masking needed
      const char* Kc = (const char*)Kl[cur];
      const char* Vc = (const char*)Vl[cur];
      f32x4 sc[4];
#pragma unroll
      for (int h = 0; h < 4; ++h) sc[h] = z4;
#pragma unroll
      for (int d = 0; d < 8; ++d){
#pragma unroll
        for (int h = 0; h < 4; ++h){
          int kr = h * 16 + lo;
          s16x8 kf = *(const s16x8*)(Kc + kr * 512 + ((d * 64 + grp * 16) ^ ((kr & 7) << 4)));
          sc[h] = MFMA16(kf, aq[d], sc[h]);   // swapped: score[key][q]
        }
      }
      uint_t pb0 = padbits[b * 64 + (kt >> 5)];
      uint_t pb1 = padbits[b * 64 + (kt >> 5) + 1];
#pragma unroll
      for (int h = 0; h < 4; ++h){
        uint_t bg = ((h < 2 ? pb0 : pb1) >> ((h & 1) * 16)) >> (4 * grp);
#pragma unroll
        for (int r = 0; r < 4; ++r){
          float v = sc[h][r] * 0.0625f;      // 1/sqrt(256)
          sc[h][r] = ((bg >> r) & 1) ? NEG : v;
        }
      }
      if (!full){                            // causal: key kt+h*16+4g+r vs q=qrow0+lo
#pragma unroll
        for (int h = 0; h < 4; ++h)
#pragma unroll
          for (int r = 0; r < 4; ++r)
            if (kt + h * 16 + 4 * grp + r > qrow0 + lo) sc[h][r] = NEG;
      }
      float mt0 = fmaxf(fmaxf(sc[0][0], sc[0][1]), fmaxf(sc[0][2], sc[0][3]));
      float mt1 = fmaxf(fmaxf(sc[1][0], sc[1][1]), fmaxf(sc[1][2], sc[1][3]));
      float mt2 = fmaxf(fmaxf(sc[2][0], sc[2][1]), fmaxf(sc[2][2], sc[2][3]));
      float mt3 = fmaxf(fmaxf(sc[3][0], sc[3][1]), fmaxf(sc[3][2], sc[3][3]));
      float mtv = fmaxf(fmaxf(mt0, mt1), fmaxf(mt2, mt3));
      mtv = fmaxf(mtv, __shfl_xor(mtv, 16));
      mtv = fmaxf(mtv, __shfl_xor(mtv, 32));
      if (__any(mtv > m_lo + 8.f)){          // deferred rescale, THR=8
        float mn = fmaxf(m_lo, mtv);
        float al = __expf(m_lo - mn);
        m_lo = mn;
        l_lo *= al;
        float a0 = __shfl(al, 4 * grp + 0);
        float a1 = __shfl(al, 4 * grp + 1);
        float a2 = __shfl(al, 4 * grp + 2);
        float a3 = __shfl(al, 4 * grp + 3);
#pragma unroll
        for (int i = 0; i < 16; ++i){
          o[i][0] *= a0; o[i][1] *= a1; o[i][2] *= a2; o[i][3] *= a3;
        }
      }
      float ls = 0.f;
#pragma unroll
      for (int h = 0; h < 4; ++h)
#pragma unroll
        for (int r = 0; r < 4; ++r){
          float p = __expf(sc[h][r] - m_lo);
          sc[h][r] = p;
          ls += p;
        }
      ls += __shfl_xor(ls, 16);
      ls += __shfl_xor(ls, 32);
      l_lo += ls;
      // P -> LDS bf16 (row = q = lo), re-fragment as PV A-operand
      char* prow = (char*)&P[w][lo][0];
#pragma unroll
      for (int h = 0; h < 4; ++h){
        uint_t u0 = (uint_t)f2b(sc[h][0]) | ((uint_t)f2b(sc[h][1]) << 16);
        uint_t u1 = (uint_t)f2b(sc[h][2]) | ((uint_t)f2b(sc[h][3]) << 16);
        *(uint_t*)(prow + h * 32 + grp * 8)     = u0;
        *(uint_t*)(prow + h * 32 + grp * 8 + 4) = u1;
      }
      s16x8 pa0 = *(const s16x8*)(prow + grp * 16);
      s16x8 pa1 = *(const s16x8*)(prow + 64 + grp * 16);
#pragma unroll
      for (int i = 0; i < 16; ++i){
        int vr = i * 16 + lo;
        s16x8 v0 = *(const s16x8*)(Vc + vr * 128 + ((grp * 16)      ^ ((vr & 7) << 4)));
        s16x8 v1 = *(const s16x8*)(Vc + vr * 128 + ((64 + grp * 16) ^ ((vr & 7) << 4)));
        o[i] = MFMA16(pa0, v0, o[i]);
        o[i] = MFMA16(pa1, v1, o[i]);
      }
    }
    __syncthreads();   // next-buf staged AND cur reads done
    cur ^= 1;
  }

  // partial out: O bf16 [slot][128][256]; m,l f32 [slot][128][2]
#pragma unroll
  for (int i = 0; i < 16; ++i)
#pragma unroll
    for (int r = 0; r < 4; ++r)
      Opart[((size_t)slot * 128 + w * 16 + grp * 4 + r) * DH_ + i * 16 + lo] = f2b(o[i][r]);
  if (grp == 0){
    mlp[((size_t)slot * 128 + w * 16 + lo) * 2]     = m_lo;
    mlp[((size_t)slot * 128 + w * 16 + lo) * 2 + 1] = l_lo;
  }
}

// ---- phase B: combine splits. block = (qp, b); 512 thr: row = t>>2, 64-col quarter ----
__global__ __launch_bounds__(512) void k_attn_comb(const ushort_t* __restrict__ Opart,
                                                   const float* __restrict__ mlp,
                                                   float* __restrict__ out){
  int qp = blockIdx.x, b = blockIdx.y;
  int nch = (qp >> 1) + 1;
  int pre = qp + ((qp - 1) * (qp - 1)) / 4;
  int base = b * 72 + pre;
  int t = threadIdx.x;
  int row = t >> 2, c0 = (t & 3) * 64;
  const float MSENT = -1e30f;

  float M = MSENT;
#pragma unroll
  for (int s = 0; s < 8; ++s)
    if (s < nch) M = fmaxf(M, mlp[((size_t)(base + s) * 128 + row) * 2]);
  float w8[8];
  float L = 0.f;
#pragma unroll
  for (int s = 0; s < 8; ++s){
    if (s < nch){
      float ms = mlp[((size_t)(base + s) * 128 + row) * 2];
      float ls = mlp[((size_t)(base + s) * 128 + row) * 2 + 1];
      float e = __expf(ms - M);
      w8[s] = e;
      L += ls * e;
    } else w8[s] = 0.f;
  }
  float Li = 1.0f / L;
  size_t orow = (size_t)(b * S_ + qp * 128 + row) * DH_;
#pragma unroll
  for (int cc = 0; cc < 8; ++cc){
    int c = c0 + cc * 8;
    float acc[8];
#pragma unroll
    for (int j = 0; j < 8; ++j) acc[j] = 0.f;
#pragma unroll
    for (int s = 0; s < 8; ++s){
      if (s < nch){
        s16x8 v = *(const s16x8*)(Opart + ((size_t)(base + s) * 128 + row) * DH_ + c);
        float ws = w8[s];
#pragma unroll
        for (int j = 0; j < 8; ++j) acc[j] += ws * b2f((ushort_t)v[j]);
      }
    }
    f32x4 o0, o1;
#pragma unroll
    for (int j = 0; j < 4; ++j){ o0[j] = acc[j] * Li; o1[j] = acc[4+j] * Li; }
    *(f32x4*)(out + orow + c) = o0;
    *(f32x4*)(out + orow + c + 4) = o1;
  }
}

extern "C" void kernel_launch(void* const* d_in, const int* in_sizes, int n_in,
                              void* d_out, int out_size, void* d_ws, size_t ws_size,
                              hipStream_t stream){
  const float* x          = (const float*)d_in[0];
  // d_in[1] = causal_mask (semantics fixed: lower-triangular) — not read
  const unsigned char* pm = (const unsigned char*)d_in[2];
  const float* Wq = (const float*)d_in[3];
  const float* bQ = (const float*)d_in[4];
  const float* Wk = (const float*)d_in[5];
  const float* bK = (const float*)d_in[6];
  const float* Wv = (const float*)d_in[7];
  const float* bV = (const float*)d_in[8];
  float* out = (float*)d_out;

  char* ws = (char*)d_ws;
  ushort_t* xbf  = (ushort_t*)(ws);              // 33,554,432 B (dead after gemm)
  ushort_t* Wt   = (ushort_t*)(ws + 33554432);   //  3,145,728 B (dead after gemm)
  ushort_t* Qb   = (ushort_t*)(ws + 36700160);   //  4,194,304 B
  ushort_t* Kb   = (ushort_t*)(ws + 40894464);   //  4,194,304 B
  ushort_t* Vb   = (ushort_t*)(ws + 45088768);   //  4,194,304 B
  ushort_t* Vt   = (ushort_t*)(ws + 49283072);   //  4,194,304 B
  uint_t*   padbits = (uint_t*)(ws + 53477376);  //      1,024 B
  // reuse (stream-ordered; gemm completes before attn): partials in xbf/Wt regions
  ushort_t* Opart = (ushort_t*)(ws);             // 288*128*256*2 = 18,874,368 B
  float*    mlp   = (float*)(ws + 33554432);     // 288*128*2*4  =    294,912 B

  k_convert_x  <<<dim3(8192),       dim3(256), 0, stream>>>(x, xbf);
  k_transpose_w<<<dim3(64, 8, 3),   dim3(256), 0, stream>>>(Wq, Wk, Wv, Wt);
  k_prep_pad   <<<dim3(1),          dim3(256), 0, stream>>>(pm, padbits);
  k_gemm_qkv   <<<dim3(64, 6),      dim3(256), 0, stream>>>(xbf, Wt, bQ, bK, bV, Qb, Kb, Vb);
  k_transpose_v<<<dim3(256, 8),     dim3(256), 0, stream>>>(Vb, Vt);
  k_attn_part  <<<dim3(8, 16, 4),   dim3(512), 0, stream>>>(Qb, Kb, Vt, padbits, Opart, mlp);
  k_attn_comb  <<<dim3(16, 4),      dim3(512), 0, stream>>>(Opart, mlp, out);
}